// Round 11
// baseline (231.390 us; speedup 1.0000x reference)
//
#include <hip/hip_runtime.h>
#include <hip/hip_bf16.h>
#include <math.h>

// Problem constants
#define Bn 2
#define Sn 2048
#define Dn 1024
#define Hn 16
#define DKn 64
#define BHS (Bn * Hn * Sn)

using fragb  = __attribute__((ext_vector_type(8))) short;      // 8 bf16
using frag16 = __attribute__((ext_vector_type(8))) _Float16;   // 8 fp16
using f4     = __attribute__((ext_vector_type(4))) float;

__device__ __forceinline__ short f2bf(float f) {
    union { float f; unsigned u; } v; v.f = f;
    unsigned r = v.u + 0x7FFF + ((v.u >> 16) & 1);   // RNE
    return (short)(r >> 16);
}
__device__ __forceinline__ unsigned short f2h(float f) {
    _Float16 h = (_Float16)f;                         // RNE
    unsigned short s; __builtin_memcpy(&s, &h, 2); return s;
}

// async global->LDS, 16B per lane; LDS dest = wave-uniform base + lane*16
#define GLOAD(gptr, lptr)                                                     \
    __builtin_amdgcn_global_load_lds(                                         \
        (const __attribute__((address_space(1))) unsigned int*)(const void*)(gptr), \
        (__attribute__((address_space(3))) unsigned int*)(void*)(lptr), 16, 0, 0)

// ---------------- prep: fp32 -> fp16 casts (x4 vectorized) + bf16 mask row --
#define NX (Bn * Sn * Dn)      // 4M
#define NW (Dn * Dn)           // 1M
#define NF4 ((NX + 4 * NW) / 4)

__global__ __launch_bounds__(256) void prep(
    const float* __restrict__ x,  const float* __restrict__ Wq,
    const float* __restrict__ Wk, const float* __restrict__ Wv,
    const float* __restrict__ Wo, const int* __restrict__ mask,
    short* __restrict__ xh,
    short* __restrict__ Wqh, short* __restrict__ Wkh,
    short* __restrict__ Wvh, short* __restrict__ Woh,
    short* __restrict__ mfb)
{
    int i = blockIdx.x * 256 + threadIdx.x;
    if (i < NF4) {
        int e = i << 2;
        const float* src; short* dst; int j;
        if (e < NX)               { src = x;  dst = xh;  j = e; }
        else if (e < NX + NW)     { src = Wq; dst = Wqh; j = e - NX; }
        else if (e < NX + 2 * NW) { src = Wk; dst = Wkh; j = e - NX - NW; }
        else if (e < NX + 3 * NW) { src = Wv; dst = Wvh; j = e - NX - 2 * NW; }
        else                      { src = Wo; dst = Woh; j = e - NX - 3 * NW; }
        float4 v = *(const float4*)(src + j);
        ushort4 o;
        o.x = f2h(v.x); o.y = f2h(v.y); o.z = f2h(v.z); o.w = f2h(v.w);
        *(ushort4*)(dst + j) = o;
    } else {
        int j = (i - NF4) << 2;
        if (j < Bn * Sn) {
            int4 m = *(const int4*)(mask + j);
            ushort4 o;
            o.x = m.x ? 0x3F80 : 0; o.y = m.y ? 0x3F80 : 0;
            o.z = m.z ? 0x3F80 : 0; o.w = m.w ? 0x3F80 : 0;
            *(ushort4*)(mfb + j) = o;
        }
    }
}

// ---------------- QKV GEMM: fp16, BK=32, LDS-transpose b128 epilogue --------
// C[M][3072] = A[M][1024]*W[n][1024]^T + bias; epilogue by widx:
//   0 -> Q bf16 (x 0.125*log2e), 1 -> K bf16, 2 -> V^T bf16 (masked)
__global__ __launch_bounds__(256) void gemm_qkv(
    const short* __restrict__ A,
    const short* __restrict__ W0, const float* __restrict__ b0,
    const short* __restrict__ W1, const float* __restrict__ b1,
    const short* __restrict__ W2, const float* __restrict__ b2,
    const int* __restrict__ mask,
    short* __restrict__ Qb, short* __restrict__ Kb, short* __restrict__ Vtb)
{
    __shared__ __align__(16) short As[128 * 32];
    __shared__ __align__(16) short Bs[128 * 32];
    __shared__ __align__(16) short Cs[64 * 130];   // epilogue transpose tile

    const int tid  = threadIdx.x;
    const int wave = tid >> 6;
    const int lane = tid & 63;
    const int quad = lane >> 4;
    const int l16  = lane & 15;
    const int wm   = wave >> 1;
    const int wn   = wave & 1;

    const int m0   = blockIdx.y * 128;
    const int n0   = blockIdx.x * 128;
    const int widx = n0 >> 10;
    const int nl0  = n0 & 1023;

    const short* Wp   = widx == 0 ? W0 : (widx == 1 ? W1 : W2);
    const float* bias = widx == 0 ? b0 : (widx == 1 ? b1 : b2);

    f4 acc[4][4];
    #pragma unroll
    for (int i = 0; i < 4; i++)
        #pragma unroll
        for (int j = 0; j < 4; j++) {
            acc[i][j][0] = 0.f; acc[i][j][1] = 0.f;
            acc[i][j][2] = 0.f; acc[i][j][3] = 0.f;
        }

    const int K = Dn;
    const int r0  = tid >> 2,         kc0 = (tid & 3) * 8;
    const int r1  = (tid + 256) >> 2;
    const short* Ar0 = A  + (size_t)(m0 + r0) * K + kc0;
    const short* Ar1 = A  + (size_t)(m0 + r1) * K + kc0;
    const short* Br0 = Wp + (size_t)(nl0 + r0) * K + kc0;
    const short* Br1 = Wp + (size_t)(nl0 + r1) * K + kc0;

    for (int k0 = 0; k0 < K; k0 += 32) {
        __syncthreads();
        GLOAD(Ar0 + k0, &As[(wave * 64) * 8]);
        GLOAD(Ar1 + k0, &As[(256 + wave * 64) * 8]);
        GLOAD(Br0 + k0, &Bs[(wave * 64) * 8]);
        GLOAD(Br1 + k0, &Bs[(256 + wave * 64) * 8]);
        __syncthreads();

        frag16 a[4], b[4];
        #pragma unroll
        for (int mi = 0; mi < 4; mi++)
            a[mi] = *(const frag16*)&As[(wm * 64 + mi * 16 + l16) * 32 + quad * 8];
        #pragma unroll
        for (int ni = 0; ni < 4; ni++)
            b[ni] = *(const frag16*)&Bs[(wn * 64 + ni * 16 + l16) * 32 + quad * 8];
        #pragma unroll
        for (int mi = 0; mi < 4; mi++)
            #pragma unroll
            for (int ni = 0; ni < 4; ni++)
                acc[mi][ni] = __builtin_amdgcn_mfma_f32_16x16x32_f16(
                    a[mi], b[ni], acc[mi][ni], 0, 0, 0);
    }

    // ---- epilogue v2: LDS transpose -> fully coalesced b128 stores ----
    const float QSCALE = 0.125f * 1.44269504088896340736f;
    const int bq_ = m0 >> 11;          // batch index (m0 multiple of 128)
    const int s0  = m0 & (Sn - 1);
    const int h0  = nl0 >> 6;

    #pragma unroll 1
    for (int rd = 0; rd < 2; rd++) {
        if (wm == rd) {
            #pragma unroll
            for (int mi = 0; mi < 4; mi++) {
                #pragma unroll
                for (int r = 0; r < 4; r++) {
                    int mrow = mi * 16 + quad * 4 + r;          // 0..63 in round
                    float mscale = 1.f;
                    if (widx == 2)
                        mscale = (float)mask[bq_ * Sn + s0 + rd * 64 + mrow];
                    #pragma unroll
                    for (int ni = 0; ni < 4; ni++) {
                        int ncol = wn * 64 + ni * 16 + l16;
                        float v = acc[mi][ni][r] + bias[nl0 + ncol];
                        if (widx == 0) v *= QSCALE;
                        if (widx == 2) v *= mscale;
                        Cs[mrow * 130 + ncol] = f2bf(v);
                    }
                }
            }
        }
        __syncthreads();
        if (widx != 2) {
            // [B][H][S][DK]: 64 s-rows x 2 heads x 64 dk -> 128B dk-runs
            short* dst = (widx == 0) ? Qb : Kb;
            #pragma unroll
            for (int it = 0; it < 4; it++) {
                int t2 = tid + it * 256;         // 0..1023
                int lm = t2 >> 4;                // s row 0..63
                int c  = t2 & 15;                // 16B unit
                uint4 vv = *(const uint4*)&Cs[lm * 130 + c * 8];
                int hh = c >> 3, dk = (c & 7) * 8;
                int sl = s0 + rd * 64 + lm;
                *(uint4*)&dst[((size_t)(bq_ * Hn + h0 + hh) * Sn + sl) * DKn + dk] = vv;
            }
        } else {
            // V^T [B][H][DK][S]: 128 dk-rows x 64 s -> 128B s-runs
            #pragma unroll
            for (int it = 0; it < 4; it++) {
                int t2 = tid + it * 256;
                int dk2 = t2 & 127;              // n index 0..127
                int c   = t2 >> 7;               // s 8-chunk 0..7
                short tmp[8];
                #pragma unroll
                for (int j = 0; j < 8; j++)
                    tmp[j] = Cs[(c * 8 + j) * 130 + dk2];
                int hh = dk2 >> 6, dk = dk2 & 63;
                int sl = s0 + rd * 64 + c * 8;
                uint4 vv; __builtin_memcpy(&vv, tmp, 16);
                *(uint4*)&Vtb[((size_t)(bq_ * Hn + h0 + hh) * DKn + dk) * Sn + sl] = vv;
            }
        }
        __syncthreads();
    }
}

// ---------------- Out GEMM: fp16, BM=64, fp32 out ---------------------------
__global__ __launch_bounds__(256) void gemm_out(
    const short* __restrict__ A, const short* __restrict__ Wp,
    const float* __restrict__ bias, float* __restrict__ outf)
{
    __shared__ __align__(16) short As[64 * 32];
    __shared__ __align__(16) short Bs[128 * 32];

    const int tid  = threadIdx.x;
    const int wave = tid >> 6;
    const int lane = tid & 63;
    const int quad = lane >> 4;
    const int l16  = lane & 15;
    const int wm   = wave >> 1;
    const int wn   = wave & 1;

    const int m0 = blockIdx.y * 64;
    const int n0 = blockIdx.x * 128;

    f4 acc[2][4];
    #pragma unroll
    for (int i = 0; i < 2; i++)
        #pragma unroll
        for (int j = 0; j < 4; j++) {
            acc[i][j][0] = 0.f; acc[i][j][1] = 0.f;
            acc[i][j][2] = 0.f; acc[i][j][3] = 0.f;
        }

    const int K = Dn;
    const int r0  = tid >> 2,         kc0 = (tid & 3) * 8;
    const int r1  = (tid + 256) >> 2;
    const short* Ar0 = A  + (size_t)(m0 + r0) * K + kc0;
    const short* Br0 = Wp + (size_t)(n0 + r0) * K + kc0;
    const short* Br1 = Wp + (size_t)(n0 + r1) * K + kc0;

    for (int k0 = 0; k0 < K; k0 += 32) {
        __syncthreads();
        GLOAD(Ar0 + k0, &As[(wave * 64) * 8]);
        GLOAD(Br0 + k0, &Bs[(wave * 64) * 8]);
        GLOAD(Br1 + k0, &Bs[(256 + wave * 64) * 8]);
        __syncthreads();

        frag16 a[2], b[4];
        #pragma unroll
        for (int mi = 0; mi < 2; mi++)
            a[mi] = *(const frag16*)&As[(wm * 32 + mi * 16 + l16) * 32 + quad * 8];
        #pragma unroll
        for (int ni = 0; ni < 4; ni++)
            b[ni] = *(const frag16*)&Bs[(wn * 64 + ni * 16 + l16) * 32 + quad * 8];
        #pragma unroll
        for (int mi = 0; mi < 2; mi++)
            #pragma unroll
            for (int ni = 0; ni < 4; ni++)
                acc[mi][ni] = __builtin_amdgcn_mfma_f32_16x16x32_f16(
                    a[mi], b[ni], acc[mi][ni], 0, 0, 0);
    }

    #pragma unroll
    for (int mi = 0; mi < 2; mi++) {
        #pragma unroll
        for (int ni = 0; ni < 4; ni++) {
            int nl = n0 + wn * 64 + ni * 16 + l16;
            float bv = bias[nl];
            #pragma unroll
            for (int r = 0; r < 4; r++) {
                int m = m0 + wm * 32 + mi * 16 + quad * 4 + r;
                outf[(size_t)m * Dn + nl] = acc[mi][ni][r] + bv;
            }
        }
    }
}

// ---------------- Flash attention: split-K x2, max-free softmax -------------
#define LP  72

__global__ __launch_bounds__(256) void attn_mfma(
    const short* __restrict__ Qb, const short* __restrict__ Kb,
    const short* __restrict__ Vtb, const short* __restrict__ mfb,
    float* __restrict__ ctxp0, float* __restrict__ ctxp1,
    float* __restrict__ lp)
{
    __shared__ __align__(16) short Ks[64 * 64];
    __shared__ __align__(16) short Vs[64 * 64];
    __shared__ short Ps[4][32 * LP];
    __shared__ __align__(16) short mfs[64];

    const int tid  = threadIdx.x;
    const int wave = tid >> 6;
    const int lane = tid & 63;
    const int quad = lane >> 4;
    const int l16  = lane & 15;

    const int split = blockIdx.x & 1;
    const int rest  = blockIdx.x >> 1;
    const int qt  = rest & 15;
    const int bhh = rest >> 4;
    const int b   = bhh >> 4;
    const int h   = bhh & 15;

    fragb qf[2][2];
    #pragma unroll
    for (int w = 0; w < 2; w++) {
        int qrow = qt * 128 + wave * 32 + w * 16 + l16;
        const short* qptr = Qb + ((size_t)bhh * Sn + qrow) * DKn + quad * 8;
        qf[w][0] = *(const fragb*)(qptr);
        qf[w][1] = *(const fragb*)(qptr + 32);
    }

    f4 ctx[2][4];
    #pragma unroll
    for (int w = 0; w < 2; w++)
        #pragma unroll
        for (int dt = 0; dt < 4; dt++) {
            ctx[w][dt][0] = 0.f; ctx[w][dt][1] = 0.f;
            ctx[w][dt][2] = 0.f; ctx[w][dt][3] = 0.f;
        }
    f4 lacc[2];
    lacc[0][0] = 0.f; lacc[0][1] = 0.f; lacc[0][2] = 0.f; lacc[0][3] = 0.f;
    lacc[1] = lacc[0];

    const int lr = lane >> 3;
    const int sc = ((lane & 7) ^ lr) * 8;
    const short* Kg = Kb  + (size_t)bhh * Sn * DKn;
    const short* Vg = Vtb + (size_t)bhh * DKn * Sn;
    const short* mg = mfb + (size_t)b * Sn;

    const short* Ksrc = Kg + (size_t)(wave * 16 + lr) * DKn + sc;
    const short* Vsrc = Vg + (size_t)(wave * 16 + lr) * Sn + sc;

    const int c0 = ((quad ^ (l16 & 7)) * 8);

    const int kt0 = split * 16;
    for (int kt = kt0; kt < kt0 + 16; kt++) {
        __syncthreads();
        GLOAD(Ksrc + (size_t)kt * 4096,             &Ks[(wave * 16) * 64]);
        GLOAD(Ksrc + (size_t)kt * 4096 + 8 * DKn,   &Ks[(wave * 16 + 8) * 64]);
        GLOAD(Vsrc + (size_t)kt * 64,               &Vs[(wave * 16) * 64]);
        GLOAD(Vsrc + (size_t)kt * 64 + 8 * Sn,      &Vs[(wave * 16 + 8) * 64]);
        if (tid < 8)
            *(uint4*)&mfs[tid * 8] = *(const uint4*)(mg + kt * 64 + tid * 8);
        __syncthreads();

        #pragma unroll
        for (int t = 0; t < 4; t++) {
            fragb k0 = *(const fragb*)&Ks[(t * 16 + l16) * 64 + c0];
            fragb k1 = *(const fragb*)&Ks[(t * 16 + l16) * 64 + (c0 ^ 32)];
            #pragma unroll
            for (int w = 0; w < 2; w++) {
                f4 a; a[0] = 0.f; a[1] = 0.f; a[2] = 0.f; a[3] = 0.f;
                a = __builtin_amdgcn_mfma_f32_16x16x32_bf16(k0, qf[w][0], a, 0, 0, 0);
                a = __builtin_amdgcn_mfma_f32_16x16x32_bf16(k1, qf[w][1], a, 0, 0, 0);
                unsigned u0 = __float_as_uint(exp2f(a[0]));
                unsigned u1 = __float_as_uint(exp2f(a[1]));
                unsigned u2 = __float_as_uint(exp2f(a[2]));
                unsigned u3 = __float_as_uint(exp2f(a[3]));
                uint2 pw;
                pw.x = __builtin_amdgcn_perm(u1, u0, 0x07060302u);
                pw.y = __builtin_amdgcn_perm(u3, u2, 0x07060302u);
                *(uint2*)&Ps[wave][(w * 16 + l16) * LP + 16 * t + quad * 4] = pw;
            }
        }

        fragb p[2][2];
        #pragma unroll
        for (int w = 0; w < 2; w++) {
            p[w][0] = *(const fragb*)&Ps[wave][(w * 16 + l16) * LP + quad * 8];
            p[w][1] = *(const fragb*)&Ps[wave][(w * 16 + l16) * LP + quad * 8 + 32];
        }
        fragb m0 = *(const fragb*)&mfs[quad * 8];
        fragb m1 = *(const fragb*)&mfs[quad * 8 + 32];
        #pragma unroll
        for (int w = 0; w < 2; w++) {
            lacc[w] = __builtin_amdgcn_mfma_f32_16x16x32_bf16(p[w][0], m0, lacc[w], 0, 0, 0);
            lacc[w] = __builtin_amdgcn_mfma_f32_16x16x32_bf16(p[w][1], m1, lacc[w], 0, 0, 0);
        }
        #pragma unroll
        for (int dt = 0; dt < 4; dt++) {
            fragb v0 = *(const fragb*)&Vs[(dt * 16 + l16) * 64 + c0];
            fragb v1 = *(const fragb*)&Vs[(dt * 16 + l16) * 64 + (c0 ^ 32)];
            #pragma unroll
            for (int w = 0; w < 2; w++) {
                ctx[w][dt] = __builtin_amdgcn_mfma_f32_16x16x32_bf16(p[w][0], v0, ctx[w][dt], 0, 0, 0);
                ctx[w][dt] = __builtin_amdgcn_mfma_f32_16x16x32_bf16(p[w][1], v1, ctx[w][dt], 0, 0, 0);
            }
        }
    }

    float* cp  = split ? ctxp1 : ctxp0;
    float* lpp = lp + (size_t)split * BHS;
    #pragma unroll
    for (int w = 0; w < 2; w++)
        #pragma unroll
        for (int r = 0; r < 4; r++) {
            int row = qt * 128 + wave * 32 + w * 16 + quad * 4 + r;
            if (l16 == 0) lpp[(size_t)bhh * Sn + row] = lacc[w][r];
            #pragma unroll
            for (int dt = 0; dt < 4; dt++)
                cp[((size_t)(b * Sn + row)) * Dn + h * DKn + dt * 16 + l16] =
                    ctx[w][dt][r];
        }
}

// ---------------- reduce: merge split partials, normalize, emit fp16 --------
__global__ __launch_bounds__(256) void reduce_ctx(
    const float* __restrict__ c0, const float* __restrict__ c1,
    const float* __restrict__ lp, short* __restrict__ Ch)
{
    int i4 = blockIdx.x * 256 + threadIdx.x;
    int e    = i4 << 2;
    int brow = e >> 10;
    int d    = e & 1023;
    int b    = brow >> 11;
    int row  = brow & (Sn - 1);
    int h    = d >> 6;
    size_t li = (size_t)(b * Hn + h) * Sn + row;
    float l = lp[li] + lp[BHS + li];
    float inv = 1.f / l;
    float4 v0 = ((const float4*)c0)[i4];
    float4 v1 = ((const float4*)c1)[i4];
    ushort4 o;
    o.x = f2h((v0.x + v1.x) * inv);
    o.y = f2h((v0.y + v1.y) * inv);
    o.z = f2h((v0.z + v1.z) * inv);
    o.w = f2h((v0.w + v1.w) * inv);
    ((ushort4*)Ch)[i4] = o;
}

// ---------------- launch ----------------
extern "C" void kernel_launch(void* const* d_in, const int* in_sizes, int n_in,
                              void* d_out, int out_size, void* d_ws, size_t ws_size,
                              hipStream_t stream) {
    const float* x    = (const float*)d_in[0];
    const int*   mask = (const int*)d_in[1];
    const float* Wq   = (const float*)d_in[2];
    const float* bq   = (const float*)d_in[3];
    const float* Wk   = (const float*)d_in[4];
    const float* bk   = (const float*)d_in[5];
    const float* Wv   = (const float*)d_in[6];
    const float* bv   = (const float*)d_in[7];
    const float* Wo   = (const float*)d_in[8];
    const float* bo   = (const float*)d_in[9];
    float* out = (float*)d_out;

    char* ws = (char*)d_ws;
    const size_t MB = 1024u * 1024u;
    short* xh    = (short*)(ws + 0 * MB);    // 8 MB fp16 (dead after QKV)
    short* Wqh   = (short*)(ws + 8 * MB);
    short* Wkh   = (short*)(ws + 10 * MB);
    short* Wvh   = (short*)(ws + 12 * MB);
    short* Qb    = (short*)(ws + 16 * MB);
    short* Kb    = (short*)(ws + 24 * MB);
    short* Vtb   = (short*)(ws + 32 * MB);
    float* ctxp0 = (float*)(ws + 0 * MB);    // overlays dead region
    float* ctxp1 = (float*)(ws + 40 * MB);
    short* Woh   = (short*)(ws + 56 * MB);
    float* lp    = (float*)(ws + 58 * MB);
    short* mfb   = (short*)(ws + 59 * MB);
    short* Ch    = (short*)(ws + 60 * MB);

    const int PRE = NF4 + (Bn * Sn) / 4;
    prep<<<(PRE + 255) / 256, 256, 0, stream>>>(
        x, Wq, Wk, Wv, Wo, mask, xh, Wqh, Wkh, Wvh, Woh, mfb);

    gemm_qkv<<<dim3(24, 32), 256, 0, stream>>>(
        xh, Wqh, bq, Wkh, bk, Wvh, bv, mask, Qb, Kb, Vtb);

    attn_mfma<<<dim3(Bn * Hn * (Sn / 128) * 2), 256, 0, stream>>>(
        Qb, Kb, Vtb, mfb, ctxp0, ctxp1, lp);

    reduce_ctx<<<dim3(NX / 4 / 256), 256, 0, stream>>>(ctxp0, ctxp1, lp, Ch);

    gemm_out<<<dim3(8, 64), 256, 0, stream>>>(Ch, Woh, bo, out);
}

// Round 12
// 214.305 us; speedup vs baseline: 1.0797x; 1.0797x over previous
//
#include <hip/hip_runtime.h>
#include <hip/hip_bf16.h>
#include <math.h>

// Problem constants
#define Bn 2
#define Sn 2048
#define Dn 1024
#define Hn 16
#define DKn 64
#define BHS (Bn * Hn * Sn)

using fragb  = __attribute__((ext_vector_type(8))) short;      // 8 bf16
using frag16 = __attribute__((ext_vector_type(8))) _Float16;   // 8 fp16
using f4     = __attribute__((ext_vector_type(4))) float;

__device__ __forceinline__ short f2bf(float f) {
    union { float f; unsigned u; } v; v.f = f;
    unsigned r = v.u + 0x7FFF + ((v.u >> 16) & 1);   // RNE
    return (short)(r >> 16);
}
__device__ __forceinline__ unsigned short f2h(float f) {
    _Float16 h = (_Float16)f;                         // RNE
    unsigned short s; __builtin_memcpy(&s, &h, 2); return s;
}

// async global->LDS, 16B per lane; LDS dest = wave-uniform base + lane*16
#define GLOAD(gptr, lptr)                                                     \
    __builtin_amdgcn_global_load_lds(                                         \
        (const __attribute__((address_space(1))) unsigned int*)(const void*)(gptr), \
        (__attribute__((address_space(3))) unsigned int*)(void*)(lptr), 16, 0, 0)

// ---------------- prep: fp32 -> fp16 casts (x4 vectorized) + bf16 mask row --
#define NX (Bn * Sn * Dn)      // 4M
#define NW (Dn * Dn)           // 1M
#define NF4 ((NX + 4 * NW) / 4)

__global__ __launch_bounds__(256) void prep(
    const float* __restrict__ x,  const float* __restrict__ Wq,
    const float* __restrict__ Wk, const float* __restrict__ Wv,
    const float* __restrict__ Wo, const int* __restrict__ mask,
    short* __restrict__ xh,
    short* __restrict__ Wqh, short* __restrict__ Wkh,
    short* __restrict__ Wvh, short* __restrict__ Woh,
    short* __restrict__ mfb)
{
    int i = blockIdx.x * 256 + threadIdx.x;
    if (i < NF4) {
        int e = i << 2;
        const float* src; short* dst; int j;
        if (e < NX)               { src = x;  dst = xh;  j = e; }
        else if (e < NX + NW)     { src = Wq; dst = Wqh; j = e - NX; }
        else if (e < NX + 2 * NW) { src = Wk; dst = Wkh; j = e - NX - NW; }
        else if (e < NX + 3 * NW) { src = Wv; dst = Wvh; j = e - NX - 2 * NW; }
        else                      { src = Wo; dst = Woh; j = e - NX - 3 * NW; }
        float4 v = *(const float4*)(src + j);
        ushort4 o;
        o.x = f2h(v.x); o.y = f2h(v.y); o.z = f2h(v.z); o.w = f2h(v.w);
        *(ushort4*)(dst + j) = o;
    } else {
        int j = (i - NF4) << 2;
        if (j < Bn * Sn) {
            int4 m = *(const int4*)(mask + j);
            ushort4 o;
            o.x = m.x ? 0x3F80 : 0; o.y = m.y ? 0x3F80 : 0;
            o.z = m.z ? 0x3F80 : 0; o.w = m.w ? 0x3F80 : 0;
            *(ushort4*)(mfb + j) = o;
        }
    }
}

// ---------------- QKV GEMM: fp16, R10-proven structure (BK=32) --------------
__global__ __launch_bounds__(256) void gemm_qkv(
    const short* __restrict__ A,
    const short* __restrict__ W0, const float* __restrict__ b0,
    const short* __restrict__ W1, const float* __restrict__ b1,
    const short* __restrict__ W2, const float* __restrict__ b2,
    const int* __restrict__ mask,
    short* __restrict__ Qb, short* __restrict__ Kb, short* __restrict__ Vtb)
{
    __shared__ __align__(16) short As[128 * 32];
    __shared__ __align__(16) short Bs[128 * 32];

    const int tid  = threadIdx.x;
    const int wave = tid >> 6;
    const int lane = tid & 63;
    const int quad = lane >> 4;
    const int l16  = lane & 15;
    const int wm   = wave >> 1;
    const int wn   = wave & 1;

    const int m0   = blockIdx.y * 128;
    const int n0   = blockIdx.x * 128;
    const int widx = n0 >> 10;
    const int nl0  = n0 & 1023;

    const short* Wp   = widx == 0 ? W0 : (widx == 1 ? W1 : W2);
    const float* bias = widx == 0 ? b0 : (widx == 1 ? b1 : b2);

    f4 acc[4][4];
    #pragma unroll
    for (int i = 0; i < 4; i++)
        #pragma unroll
        for (int j = 0; j < 4; j++) {
            acc[i][j][0] = 0.f; acc[i][j][1] = 0.f;
            acc[i][j][2] = 0.f; acc[i][j][3] = 0.f;
        }

    const int K = Dn;
    const int r0  = tid >> 2,         kc0 = (tid & 3) * 8;
    const int r1  = (tid + 256) >> 2;
    const short* Ar0 = A  + (size_t)(m0 + r0) * K + kc0;
    const short* Ar1 = A  + (size_t)(m0 + r1) * K + kc0;
    const short* Br0 = Wp + (size_t)(nl0 + r0) * K + kc0;
    const short* Br1 = Wp + (size_t)(nl0 + r1) * K + kc0;

    for (int k0 = 0; k0 < K; k0 += 32) {
        __syncthreads();
        GLOAD(Ar0 + k0, &As[(wave * 64) * 8]);
        GLOAD(Ar1 + k0, &As[(256 + wave * 64) * 8]);
        GLOAD(Br0 + k0, &Bs[(wave * 64) * 8]);
        GLOAD(Br1 + k0, &Bs[(256 + wave * 64) * 8]);
        __syncthreads();

        frag16 a[4], b[4];
        #pragma unroll
        for (int mi = 0; mi < 4; mi++)
            a[mi] = *(const frag16*)&As[(wm * 64 + mi * 16 + l16) * 32 + quad * 8];
        #pragma unroll
        for (int ni = 0; ni < 4; ni++)
            b[ni] = *(const frag16*)&Bs[(wn * 64 + ni * 16 + l16) * 32 + quad * 8];
        #pragma unroll
        for (int mi = 0; mi < 4; mi++)
            #pragma unroll
            for (int ni = 0; ni < 4; ni++)
                acc[mi][ni] = __builtin_amdgcn_mfma_f32_16x16x32_f16(
                    a[mi], b[ni], acc[mi][ni], 0, 0, 0);
    }

    const float QSCALE = 0.125f * 1.44269504088896340736f;

    #pragma unroll
    for (int mi = 0; mi < 4; mi++) {
        #pragma unroll
        for (int ni = 0; ni < 4; ni++) {
            int nl = nl0 + wn * 64 + ni * 16 + l16;
            float bv = bias[nl];
            #pragma unroll
            for (int r = 0; r < 4; r++) {
                int m = m0 + wm * 64 + mi * 16 + quad * 4 + r;
                float v = acc[mi][ni][r] + bv;
                int b  = m >> 11, s = m & (Sn - 1);
                int h  = nl >> 6, dk = nl & 63;
                if (widx == 0)
                    Qb[((size_t)(b * Hn + h) * Sn + s) * DKn + dk] = f2bf(v * QSCALE);
                else if (widx == 1)
                    Kb[((size_t)(b * Hn + h) * Sn + s) * DKn + dk] = f2bf(v);
                else {
                    float mv = (float)mask[b * Sn + s];
                    Vtb[((size_t)(b * Hn + h) * DKn + dk) * Sn + s] = f2bf(v * mv);
                }
            }
        }
    }
}

// ---------------- Out GEMM: fp16, BM=64, fp32 out ---------------------------
__global__ __launch_bounds__(256) void gemm_out(
    const short* __restrict__ A, const short* __restrict__ Wp,
    const float* __restrict__ bias, float* __restrict__ outf)
{
    __shared__ __align__(16) short As[64 * 32];
    __shared__ __align__(16) short Bs[128 * 32];

    const int tid  = threadIdx.x;
    const int wave = tid >> 6;
    const int lane = tid & 63;
    const int quad = lane >> 4;
    const int l16  = lane & 15;
    const int wm   = wave >> 1;
    const int wn   = wave & 1;

    const int m0 = blockIdx.y * 64;
    const int n0 = blockIdx.x * 128;

    f4 acc[2][4];
    #pragma unroll
    for (int i = 0; i < 2; i++)
        #pragma unroll
        for (int j = 0; j < 4; j++) {
            acc[i][j][0] = 0.f; acc[i][j][1] = 0.f;
            acc[i][j][2] = 0.f; acc[i][j][3] = 0.f;
        }

    const int K = Dn;
    const int r0  = tid >> 2,         kc0 = (tid & 3) * 8;
    const int r1  = (tid + 256) >> 2;
    const short* Ar0 = A  + (size_t)(m0 + r0) * K + kc0;
    const short* Br0 = Wp + (size_t)(n0 + r0) * K + kc0;
    const short* Br1 = Wp + (size_t)(n0 + r1) * K + kc0;

    for (int k0 = 0; k0 < K; k0 += 32) {
        __syncthreads();
        GLOAD(Ar0 + k0, &As[(wave * 64) * 8]);
        GLOAD(Br0 + k0, &Bs[(wave * 64) * 8]);
        GLOAD(Br1 + k0, &Bs[(256 + wave * 64) * 8]);
        __syncthreads();

        frag16 a[2], b[4];
        #pragma unroll
        for (int mi = 0; mi < 2; mi++)
            a[mi] = *(const frag16*)&As[(wm * 32 + mi * 16 + l16) * 32 + quad * 8];
        #pragma unroll
        for (int ni = 0; ni < 4; ni++)
            b[ni] = *(const frag16*)&Bs[(wn * 64 + ni * 16 + l16) * 32 + quad * 8];
        #pragma unroll
        for (int mi = 0; mi < 2; mi++)
            #pragma unroll
            for (int ni = 0; ni < 4; ni++)
                acc[mi][ni] = __builtin_amdgcn_mfma_f32_16x16x32_f16(
                    a[mi], b[ni], acc[mi][ni], 0, 0, 0);
    }

    #pragma unroll
    for (int mi = 0; mi < 2; mi++) {
        #pragma unroll
        for (int ni = 0; ni < 4; ni++) {
            int nl = n0 + wn * 64 + ni * 16 + l16;
            float bv = bias[nl];
            #pragma unroll
            for (int r = 0; r < 4; r++) {
                int m = m0 + wm * 32 + mi * 16 + quad * 4 + r;
                outf[(size_t)m * Dn + nl] = acc[mi][ni][r] + bv;
            }
        }
    }
}

// ---------------- Flash attention: split-K x2, raw v_exp_f32 softmax --------
#define LP  72

__global__ __launch_bounds__(256) void attn_mfma(
    const short* __restrict__ Qb, const short* __restrict__ Kb,
    const short* __restrict__ Vtb, const short* __restrict__ mfb,
    float* __restrict__ ctxp0, float* __restrict__ ctxp1,
    float* __restrict__ lp)
{
    __shared__ __align__(16) short Ks[64 * 64];
    __shared__ __align__(16) short Vs[64 * 64];
    __shared__ short Ps[4][32 * LP];
    __shared__ __align__(16) short mfs[64];

    const int tid  = threadIdx.x;
    const int wave = tid >> 6;
    const int lane = tid & 63;
    const int quad = lane >> 4;
    const int l16  = lane & 15;

    const int split = blockIdx.x & 1;
    const int rest  = blockIdx.x >> 1;
    const int qt  = rest & 15;
    const int bhh = rest >> 4;
    const int b   = bhh >> 4;
    const int h   = bhh & 15;

    fragb qf[2][2];
    #pragma unroll
    for (int w = 0; w < 2; w++) {
        int qrow = qt * 128 + wave * 32 + w * 16 + l16;
        const short* qptr = Qb + ((size_t)bhh * Sn + qrow) * DKn + quad * 8;
        qf[w][0] = *(const fragb*)(qptr);
        qf[w][1] = *(const fragb*)(qptr + 32);
    }

    f4 ctx[2][4];
    #pragma unroll
    for (int w = 0; w < 2; w++)
        #pragma unroll
        for (int dt = 0; dt < 4; dt++) {
            ctx[w][dt][0] = 0.f; ctx[w][dt][1] = 0.f;
            ctx[w][dt][2] = 0.f; ctx[w][dt][3] = 0.f;
        }
    f4 lacc[2];
    lacc[0][0] = 0.f; lacc[0][1] = 0.f; lacc[0][2] = 0.f; lacc[0][3] = 0.f;
    lacc[1] = lacc[0];

    const int lr = lane >> 3;
    const int sc = ((lane & 7) ^ lr) * 8;
    const short* Kg = Kb  + (size_t)bhh * Sn * DKn;
    const short* Vg = Vtb + (size_t)bhh * DKn * Sn;
    const short* mg = mfb + (size_t)b * Sn;

    const short* Ksrc = Kg + (size_t)(wave * 16 + lr) * DKn + sc;
    const short* Vsrc = Vg + (size_t)(wave * 16 + lr) * Sn + sc;

    const int c0 = ((quad ^ (l16 & 7)) * 8);

    const int kt0 = split * 16;
    for (int kt = kt0; kt < kt0 + 16; kt++) {
        __syncthreads();
        GLOAD(Ksrc + (size_t)kt * 4096,             &Ks[(wave * 16) * 64]);
        GLOAD(Ksrc + (size_t)kt * 4096 + 8 * DKn,   &Ks[(wave * 16 + 8) * 64]);
        GLOAD(Vsrc + (size_t)kt * 64,               &Vs[(wave * 16) * 64]);
        GLOAD(Vsrc + (size_t)kt * 64 + 8 * Sn,      &Vs[(wave * 16 + 8) * 64]);
        if (tid < 8)
            *(uint4*)&mfs[tid * 8] = *(const uint4*)(mg + kt * 64 + tid * 8);
        __syncthreads();

        #pragma unroll
        for (int t = 0; t < 4; t++) {
            fragb k0 = *(const fragb*)&Ks[(t * 16 + l16) * 64 + c0];
            fragb k1 = *(const fragb*)&Ks[(t * 16 + l16) * 64 + (c0 ^ 32)];
            #pragma unroll
            for (int w = 0; w < 2; w++) {
                f4 a; a[0] = 0.f; a[1] = 0.f; a[2] = 0.f; a[3] = 0.f;
                a = __builtin_amdgcn_mfma_f32_16x16x32_bf16(k0, qf[w][0], a, 0, 0, 0);
                a = __builtin_amdgcn_mfma_f32_16x16x32_bf16(k1, qf[w][1], a, 0, 0, 0);
                // raw v_exp_f32 (log2e folded into Q): 1 instr vs OCML's ~8
                unsigned u0 = __float_as_uint(__builtin_amdgcn_exp2f(a[0]));
                unsigned u1 = __float_as_uint(__builtin_amdgcn_exp2f(a[1]));
                unsigned u2 = __float_as_uint(__builtin_amdgcn_exp2f(a[2]));
                unsigned u3 = __float_as_uint(__builtin_amdgcn_exp2f(a[3]));
                uint2 pw;
                pw.x = __builtin_amdgcn_perm(u1, u0, 0x07060302u);
                pw.y = __builtin_amdgcn_perm(u3, u2, 0x07060302u);
                *(uint2*)&Ps[wave][(w * 16 + l16) * LP + 16 * t + quad * 4] = pw;
            }
        }

        fragb p[2][2];
        #pragma unroll
        for (int w = 0; w < 2; w++) {
            p[w][0] = *(const fragb*)&Ps[wave][(w * 16 + l16) * LP + quad * 8];
            p[w][1] = *(const fragb*)&Ps[wave][(w * 16 + l16) * LP + quad * 8 + 32];
        }
        fragb m0 = *(const fragb*)&mfs[quad * 8];
        fragb m1 = *(const fragb*)&mfs[quad * 8 + 32];
        #pragma unroll
        for (int w = 0; w < 2; w++) {
            lacc[w] = __builtin_amdgcn_mfma_f32_16x16x32_bf16(p[w][0], m0, lacc[w], 0, 0, 0);
            lacc[w] = __builtin_amdgcn_mfma_f32_16x16x32_bf16(p[w][1], m1, lacc[w], 0, 0, 0);
        }
        #pragma unroll
        for (int dt = 0; dt < 4; dt++) {
            fragb v0 = *(const fragb*)&Vs[(dt * 16 + l16) * 64 + c0];
            fragb v1 = *(const fragb*)&Vs[(dt * 16 + l16) * 64 + (c0 ^ 32)];
            #pragma unroll
            for (int w = 0; w < 2; w++) {
                ctx[w][dt] = __builtin_amdgcn_mfma_f32_16x16x32_bf16(p[w][0], v0, ctx[w][dt], 0, 0, 0);
                ctx[w][dt] = __builtin_amdgcn_mfma_f32_16x16x32_bf16(p[w][1], v1, ctx[w][dt], 0, 0, 0);
            }
        }
    }

    float* cp  = split ? ctxp1 : ctxp0;
    float* lpp = lp + (size_t)split * BHS;
    #pragma unroll
    for (int w = 0; w < 2; w++)
        #pragma unroll
        for (int r = 0; r < 4; r++) {
            int row = qt * 128 + wave * 32 + w * 16 + quad * 4 + r;
            if (l16 == 0) lpp[(size_t)bhh * Sn + row] = lacc[w][r];
            #pragma unroll
            for (int dt = 0; dt < 4; dt++)
                cp[((size_t)(b * Sn + row)) * Dn + h * DKn + dt * 16 + l16] =
                    ctx[w][dt][r];
        }
}

// ---------------- reduce: merge split partials, normalize, emit fp16 --------
__global__ __launch_bounds__(256) void reduce_ctx(
    const float* __restrict__ c0, const float* __restrict__ c1,
    const float* __restrict__ lp, short* __restrict__ Ch)
{
    int i4 = blockIdx.x * 256 + threadIdx.x;
    int e    = i4 << 2;
    int brow = e >> 10;
    int d    = e & 1023;
    int b    = brow >> 11;
    int row  = brow & (Sn - 1);
    int h    = d >> 6;
    size_t li = (size_t)(b * Hn + h) * Sn + row;
    float l = lp[li] + lp[BHS + li];
    float inv = 1.f / l;
    float4 v0 = ((const float4*)c0)[i4];
    float4 v1 = ((const float4*)c1)[i4];
    ushort4 o;
    o.x = f2h((v0.x + v1.x) * inv);
    o.y = f2h((v0.y + v1.y) * inv);
    o.z = f2h((v0.z + v1.z) * inv);
    o.w = f2h((v0.w + v1.w) * inv);
    ((ushort4*)Ch)[i4] = o;
}

// ---------------- launch ----------------
extern "C" void kernel_launch(void* const* d_in, const int* in_sizes, int n_in,
                              void* d_out, int out_size, void* d_ws, size_t ws_size,
                              hipStream_t stream) {
    const float* x    = (const float*)d_in[0];
    const int*   mask = (const int*)d_in[1];
    const float* Wq   = (const float*)d_in[2];
    const float* bq   = (const float*)d_in[3];
    const float* Wk   = (const float*)d_in[4];
    const float* bk   = (const float*)d_in[5];
    const float* Wv   = (const float*)d_in[6];
    const float* bv   = (const float*)d_in[7];
    const float* Wo   = (const float*)d_in[8];
    const float* bo   = (const float*)d_in[9];
    float* out = (float*)d_out;

    char* ws = (char*)d_ws;
    const size_t MB = 1024u * 1024u;
    short* xh    = (short*)(ws + 0 * MB);    // 8 MB fp16 (dead after QKV)
    short* Wqh   = (short*)(ws + 8 * MB);
    short* Wkh   = (short*)(ws + 10 * MB);
    short* Wvh   = (short*)(ws + 12 * MB);
    short* Qb    = (short*)(ws + 16 * MB);
    short* Kb    = (short*)(ws + 24 * MB);
    short* Vtb   = (short*)(ws + 32 * MB);
    float* ctxp0 = (float*)(ws + 0 * MB);    // overlays dead region
    float* ctxp1 = (float*)(ws + 40 * MB);
    short* Woh   = (short*)(ws + 56 * MB);
    float* lp    = (float*)(ws + 58 * MB);
    short* mfb   = (short*)(ws + 59 * MB);
    short* Ch    = (short*)(ws + 60 * MB);

    const int PRE = NF4 + (Bn * Sn) / 4;
    prep<<<(PRE + 255) / 256, 256, 0, stream>>>(
        x, Wq, Wk, Wv, Wo, mask, xh, Wqh, Wkh, Wvh, Woh, mfb);

    gemm_qkv<<<dim3(24, 32), 256, 0, stream>>>(
        xh, Wqh, bq, Wkh, bk, Wvh, bv, mask, Qb, Kb, Vtb);

    attn_mfma<<<dim3(Bn * Hn * (Sn / 128) * 2), 256, 0, stream>>>(
        Qb, Kb, Vtb, mfb, ctxp0, ctxp1, lp);

    reduce_ctx<<<dim3(NX / 4 / 256), 256, 0, stream>>>(ctxp0, ctxp1, lp, Ch);

    gemm_out<<<dim3(8, 64), 256, 0, stream>>>(Ch, Woh, bo, out);
}